// Round 9
// baseline (239.342 us; speedup 1.0000x reference)
//
#include <hip/hip_runtime.h>
#include <stdint.h>

#define TB 256
#define SCALE 0.17677669529663687f  // 1/sqrt(32)

typedef __attribute__((ext_vector_type(8))) short short8;
typedef __attribute__((ext_vector_type(4))) float f32x4;
#define MFMA(a, b, c) __builtin_amdgcn_mfma_f32_16x16x32_bf16(a, b, c, 0, 0, 0)

__device__ __forceinline__ float bf2f(uint16_t u) {
    union { uint32_t i; float f; } v; v.i = ((uint32_t)u) << 16; return v.f;
}
__device__ __forceinline__ uint16_t f2bf(float f) {
    union { float f; uint32_t i; } v; v.f = f;
    uint32_t r = v.i + 0x7fffu + ((v.i >> 16) & 1u);
    return (uint16_t)(r >> 16);
}
// xs: row n, channel c, stride 64 with 8-chunk XOR swizzle
__device__ __forceinline__ int swz(int n, int c)  { return (n << 6) + (c ^ ((n & 7) << 3)); }
// wol: row oc (64), s (32)
__device__ __forceinline__ int oswz(int oc, int s){ return (oc << 5) + (s ^ ((oc & 3) << 3)); }

// ---------------- K1: light positional embedding -> le[b][i][j][s] (bf16) ----------------
__global__ void light_emb_kernel(const float* __restrict__ light,
                                 const float* __restrict__ lw1, const float* __restrict__ lb1,
                                 const float* __restrict__ lw2, const float* __restrict__ lb2,
                                 const float* __restrict__ lw3, const float* __restrict__ lb3,
                                 uint16_t* __restrict__ le) {
    int e = blockIdx.x * 256 + threadIdx.x;
    if (e >= 4 * 33 * 33) return;
    int j = e % 33;
    int i = (e / 33) % 33;
    int b = e / (33 * 33);
    float d[3];
    #pragma unroll
    for (int c = 0; c < 3; ++c) {
        float a  = (i < 32) ? light[(b * 3 + c) * 32 + i] : -1.0f;
        float bb = (j < 32) ? light[(b * 3 + c) * 32 + j] : -1.0f;
        d[c] = a - bb;
    }
    float h1[8];
    #pragma unroll
    for (int o = 0; o < 8; ++o) {
        float s = lb1[o];
        #pragma unroll
        for (int c = 0; c < 3; ++c) s += lw1[o * 3 + c] * d[c];
        h1[o] = (s >= 0.f) ? s : 0.1f * s;
    }
    float h2[16];
    #pragma unroll
    for (int o = 0; o < 16; ++o) {
        float s = lb2[o];
        #pragma unroll
        for (int c = 0; c < 8; ++c) s += lw2[o * 8 + c] * h1[c];
        h2[o] = (s >= 0.f) ? s : 0.1f * s;
    }
    uint16_t* dst = le + (size_t)e * 32;
    #pragma unroll
    for (int o = 0; o < 32; ++o) {
        float s = lb3[o];
        #pragma unroll
        for (int c = 0; c < 16; ++c) s += lw3[o * 16 + c] * h2[c];
        dst[o] = f2bf(s);
    }
}

// LDS pool. Arenas (4 x 7840 = 31360) alias xs (132 rows x 128B = 16896 <= 31360).
// Per-pixel arena: [0,2640) kT -> sc -> abf -> ob ; [2640,5280) qT -> ao(stride 64, spans into v2)
//                  [5280,7840) v2
#define ARENA_SZ 7840
#define WOL_OFF  31360   // [64][32] bf16 swizzled = 4096
#define BIAS_OFF 35456   // f32[96]
#define BOL_OFF  35840   // f32[64]
#define POOL_SZ  36096   // 35.3 KB -> 4 blocks/CU

__global__ void __launch_bounds__(TB, 4)
fused_attn_kernel(const float* __restrict__ x,
                  const float* __restrict__ wk, const float* __restrict__ bk,
                  const float* __restrict__ wq, const float* __restrict__ bq,
                  const float* __restrict__ wv, const float* __restrict__ bv,
                  const float* __restrict__ wo, const float* __restrict__ bo,
                  const uint16_t* __restrict__ le,
                  float* __restrict__ out) {
    __shared__ __align__(16) unsigned char pool[POOL_SZ];
    uint16_t* xs   = (uint16_t*)pool;
    uint16_t* wol  = (uint16_t*)(pool + WOL_OFF);
    float*    bias = (float*)(pool + BIAS_OFF);
    float*    bol  = (float*)(pool + BOL_OFF);

    const int t = threadIdx.x;
    // XCD swizzle: the 16 w-tiles of one (b,h) land on the same XCD, adjacent in dispatch
    const int i_  = blockIdx.x;       // 12 bits: [11:7]=bh_hi, [6:3]=w-tile, [2:0]=bh_lo
    const int w0  = ((i_ >> 3) & 15) << 2;
    const int bh  = ((i_ >> 7) << 3) | (i_ & 7);
    const int b   = bh >> 6;
    const int h   = bh & 63;

    const int lane = t & 63, px = t >> 6;      // wave == pixel (4 waves)
    const int lrow = lane & 15;
    const int lk   = (lane >> 4) << 3;          // k-chunk base (8 bf16)
    const int drow = (lane >> 4) << 2;          // D-row base

    uint16_t* kT = (uint16_t*)(pool + px * ARENA_SZ);   // later sc/abf/ob
    uint16_t* qT = kT + 1320;                           // +2640 B; later ao
    uint16_t* v2 = kT + 2640;                           // +5280 B
    uint16_t* ao = qT;

    // ---- A-frags: projection weights straight from global (L2-hot), bf16 convert ----
    short8 af[6][2];
    {
        const float* wsel[3] = { wk, wq, wv };
        #pragma unroll
        for (int mt = 0; mt < 6; ++mt) {
            const float* wp = wsel[mt >> 1] + ((mt & 1) * 16 + lrow) * 64;
            #pragma unroll
            for (int hf = 0; hf < 2; ++hf) {
                float4 lo = *(const float4*)&wp[hf * 32 + lk];
                float4 hi = *(const float4*)&wp[hf * 32 + lk + 4];
                short8 v;
                v[0] = f2bf(lo.x); v[1] = f2bf(lo.y); v[2] = f2bf(lo.z); v[3] = f2bf(lo.w);
                v[4] = f2bf(hi.x); v[5] = f2bf(hi.y); v[6] = f2bf(hi.z); v[7] = f2bf(hi.w);
                af[mt][hf] = v;
            }
        }
    }

    // ---- P0: stage bias/wol + x -> xs (bf16, swizzled, ushort4-packed) ----
    if (t < 96) bias[t] = (t < 32) ? bk[t] : (t < 64) ? bq[t - 32] : bv[t - 64];
    for (int e = t; e < 64 * 32; e += TB) {
        int oc = e >> 5, s = e & 31;
        wol[oswz(oc, s)] = (oc < 61) ? f2bf(wo[oc * 32 + s]) : (uint16_t)0;
    }
    if (t < 64) bol[t] = (t < 61) ? bo[t] : 0.f;
    #pragma unroll
    for (int u = 0; u < 2; ++u) {
        int unit = t + u * 256;             // (cg, m): cg 0..15, m 0..31
        int cg = unit >> 5, m = unit & 31;
        int c0 = cg * 4;
        float4 xv[4];
        #pragma unroll
        for (int i = 0; i < 4; ++i)
            xv[i] = *(const float4*)&x[(((size_t)(b * 64 + c0 + i) * 32 + m) * 64 + h) * 64 + w0];
        #pragma unroll
        for (int p = 0; p < 4; ++p) {
            ushort4 pk = make_ushort4(f2bf(((const float*)&xv[0])[p]),
                                      f2bf(((const float*)&xv[1])[p]),
                                      f2bf(((const float*)&xv[2])[p]),
                                      f2bf(((const float*)&xv[3])[p]));
            *(ushort4*)&xs[swz(p * 33 + m + 1, c0)] = pk;
        }
    }
    __syncthreads();   // BAR1: xs + wol + bias staged

    // ---- A2: extra token (m=0) = max over m=1..32 (own pixel) ----
    {
        const int c = lane;
        float mx = bf2f(xs[swz(px * 33 + 1, c)]);
        #pragma unroll
        for (int m = 2; m <= 32; ++m) mx = fmaxf(mx, bf2f(xs[swz(px * 33 + m, c)]));
        xs[swz(px * 33, c)] = f2bf(mx);
    }

    // ---- B-frags from xs (xs dies after this) ----
    short8 bfr[3][2];
    #pragma unroll
    for (int nt = 0; nt < 3; ++nt) {
        int n = px * 33 + nt * 16 + lrow;   // may read garbage rows (discarded)
        bfr[nt][0] = *(const short8*)&xs[swz(n, lk)];
        bfr[nt][1] = *(const short8*)&xs[swz(n, 32 + lk)];
    }
    __syncthreads();   // BAR2: frags in regs; arenas may overwrite xs

    // ---- B: projections. D[q][m] = W[q][c] * xs[m][c]^T + bias ----
    #pragma unroll
    for (int mt = 0; mt < 6; ++mt) {
        int q0 = mt * 16 + drow;
        #pragma unroll
        for (int nt = 0; nt < 3; ++nt) {
            f32x4 acc = { bias[q0], bias[q0 + 1], bias[q0 + 2], bias[q0 + 3] };
            acc = MFMA(af[mt][0], bfr[nt][0], acc);
            acc = MFMA(af[mt][1], bfr[nt][1], acc);
            int m = nt * 16 + lrow;
            if (m <= 32) {
                if (q0 < 32) {
                    *(ushort4*)&kT[m * 40 + q0] =
                        make_ushort4(f2bf(acc[0]), f2bf(acc[1]), f2bf(acc[2]), f2bf(acc[3]));
                } else if (q0 < 64) {
                    *(ushort4*)&qT[m * 40 + (q0 - 32)] =
                        make_ushort4(f2bf(acc[0]), f2bf(acc[1]), f2bf(acc[2]), f2bf(acc[3]));
                } else {
                    #pragma unroll
                    for (int r = 0; r < 4; ++r)
                        v2[(q0 - 64 + r) * 40 + m] = f2bf(acc[r]);
                }
            }
        }
    }

    // ---- C1: raw scores sc[jp][i] (bf16, overwrites kT after reads) ----
    {
        short8 ka[3], qb[2];
        #pragma unroll
        for (int mt = 0; mt < 3; ++mt) ka[mt] = *(const short8*)&kT[(mt * 16 + lrow) * 40 + lk];
        #pragma unroll
        for (int jh = 0; jh < 2; ++jh) qb[jh] = *(const short8*)&qT[(1 + jh * 16 + lrow) * 40 + lk];
        f32x4 sa[3][2];
        #pragma unroll
        for (int mt = 0; mt < 3; ++mt)
            #pragma unroll
            for (int jh = 0; jh < 2; ++jh) {
                f32x4 z = { 0.f, 0.f, 0.f, 0.f };
                sa[mt][jh] = MFMA(ka[mt], qb[jh], z);
            }
        uint16_t* sc = kT;
        #pragma unroll
        for (int jh = 0; jh < 2; ++jh) {
            int jp = jh * 16 + lrow;
            #pragma unroll
            for (int mt = 0; mt < 2; ++mt) {
                int i0 = mt * 16 + drow;
                *(ushort4*)&sc[jp * 40 + i0] =
                    make_ushort4(f2bf(sa[mt][jh][0]), f2bf(sa[mt][jh][1]),
                                 f2bf(sa[mt][jh][2]), f2bf(sa[mt][jh][3]));
            }
            if (drow == 0) sc[jp * 40 + 32] = f2bf(sa[2][jh][0]);
        }
    }

    // ---- C2a: softmax over i per column jp (lane halves split i, shfl combine) ----
    {
        uint16_t* sc = kT;
        const int jp = lane & 31, hi = lane >> 5;
        const int ib = hi ? 16 : 0;
        float v[17];
        #pragma unroll
        for (int g = 0; g < 4; ++g) {
            ushort4 u = *(const ushort4*)&sc[jp * 40 + ib + g * 4];
            v[g * 4 + 0] = bf2f(u.x); v[g * 4 + 1] = bf2f(u.y);
            v[g * 4 + 2] = bf2f(u.z); v[g * 4 + 3] = bf2f(u.w);
        }
        if (hi) v[16] = bf2f(sc[jp * 40 + 32]);
        float mx = v[0];
        #pragma unroll
        for (int k = 1; k < 16; ++k) mx = fmaxf(mx, v[k]);
        if (hi) mx = fmaxf(mx, v[16]);
        mx = fmaxf(mx, __shfl_xor(mx, 32, 64));
        float sum = 0.f;
        #pragma unroll
        for (int k = 0; k < 16; ++k) { v[k] = __expf((v[k] - mx) * SCALE); sum += v[k]; }
        if (hi) { v[16] = __expf((v[16] - mx) * SCALE); sum += v[16]; }
        sum += __shfl_xor(sum, 32, 64);
        float r = 1.0f / sum;
        #pragma unroll
        for (int g = 0; g < 4; ++g) {
            *(ushort4*)&sc[jp * 40 + ib + g * 4] =
                make_ushort4(f2bf(v[g * 4 + 0] * r), f2bf(v[g * 4 + 1] * r),
                             f2bf(v[g * 4 + 2] * r), f2bf(v[g * 4 + 3] * r));
        }
        if (hi) sc[jp * 40 + 32] = f2bf(v[16] * r);
    }
    __syncthreads();   // BAR3: all sc + qT stable

    // ---- C2b (block-coop): per key-row k, bias[px][j] = sum_s q[px][s][k]*le[s][k][j]
    //      one MFMA covers all 4 pixels; wave px owns k = 8*px..8*px+7 (+32 on wave 0)
    {
        const uint16_t* leb = le + (size_t)b * (33 * 33 * 32);
        const int pxs = lrow & 3;
        const uint16_t* qsrc = (const uint16_t*)(pool + pxs * ARENA_SZ) + 1320;
        #pragma unroll
        for (int qi = 0; qi < 8; ++qi) {
            int k = px * 8 + qi;
            short8 aq = *(const short8*)&qsrc[k * 40 + lk];
            short8 b0 = *(const short8*)&leb[(k * 33 + 1 + lrow) * 32 + lk];
            short8 b1 = *(const short8*)&leb[(k * 33 + 17 + lrow) * 32 + lk];
            f32x4 z = { 0.f, 0.f, 0.f, 0.f };
            f32x4 r0 = MFMA(aq, b0, z);
            f32x4 r1 = MFMA(aq, b1, z);
            if (lane < 16) {
                #pragma unroll
                for (int r = 0; r < 4; ++r) {     // D row r = pixel r
                    uint16_t* scp = (uint16_t*)(pool + r * ARENA_SZ);
                    int o0 = lrow * 40 + k, o1 = (16 + lrow) * 40 + k;
                    scp[o0] = f2bf(bf2f(scp[o0]) + r0[r]);
                    scp[o1] = f2bf(bf2f(scp[o1]) + r1[r]);
                }
            }
        }
        if (px == 0) {
            const int k = 32;
            short8 aq = *(const short8*)&qsrc[k * 40 + lk];
            short8 b0 = *(const short8*)&leb[(k * 33 + 1 + lrow) * 32 + lk];
            short8 b1 = *(const short8*)&leb[(k * 33 + 17 + lrow) * 32 + lk];
            f32x4 z = { 0.f, 0.f, 0.f, 0.f };
            f32x4 r0 = MFMA(aq, b0, z);
            f32x4 r1 = MFMA(aq, b1, z);
            if (lane < 16) {
                #pragma unroll
                for (int r = 0; r < 4; ++r) {
                    uint16_t* scp = (uint16_t*)(pool + r * ARENA_SZ);
                    int o0 = lrow * 40 + k, o1 = (16 + lrow) * 40 + k;
                    scp[o0] = f2bf(bf2f(scp[o0]) + r0[r]);
                    scp[o1] = f2bf(bf2f(scp[o1]) + r1[r]);
                }
            }
        }
    }
    __syncthreads();   // BAR4: bias applied, qT free

    // ---- C3: o[s][jp] = sum_m v2[s][m]*a[jp][m] (+ m=32 tail); ob overwrites abf ----
    {
        uint16_t* abf = kT;
        short8 va[2], bb[2];
        #pragma unroll
        for (int st = 0; st < 2; ++st) va[st] = *(const short8*)&v2[(st * 16 + lrow) * 40 + lk];
        #pragma unroll
        for (int jt = 0; jt < 2; ++jt) bb[jt] = *(const short8*)&abf[(jt * 16 + lrow) * 40 + lk];
        f32x4 oacc[2][2];
        #pragma unroll
        for (int st = 0; st < 2; ++st)
            #pragma unroll
            for (int jt = 0; jt < 2; ++jt) {
                f32x4 z = { 0.f, 0.f, 0.f, 0.f };
                oacc[st][jt] = MFMA(va[st], bb[jt], z);
            }
        float a32[2], vt[2][4];
        #pragma unroll
        for (int jt = 0; jt < 2; ++jt) a32[jt] = bf2f(abf[(jt * 16 + lrow) * 40 + 32]);
        #pragma unroll
        for (int st = 0; st < 2; ++st)
            #pragma unroll
            for (int r = 0; r < 4; ++r) vt[st][r] = bf2f(v2[(st * 16 + drow + r) * 40 + 32]);
        uint16_t* ob = kT;
        #pragma unroll
        for (int st = 0; st < 2; ++st)
            #pragma unroll
            for (int jt = 0; jt < 2; ++jt) {
                #pragma unroll
                for (int r = 0; r < 4; ++r) oacc[st][jt][r] += vt[st][r] * a32[jt];
                int s0 = st * 16 + drow, jp = jt * 16 + lrow;
                *(ushort4*)&ob[jp * 40 + s0] =
                    make_ushort4(f2bf(oacc[st][jt][0]), f2bf(oacc[st][jt][1]),
                                 f2bf(oacc[st][jt][2]), f2bf(oacc[st][jt][3]));
            }
    }

    // ---- D: ao[jp][oc] = wo @ o + bo (ao overwrites qT, stride-64 swizzled) ----
    {
        uint16_t* ob = kT;
        short8 wa[4], obf[2];
        #pragma unroll
        for (int ot = 0; ot < 4; ++ot) wa[ot] = *(const short8*)&wol[oswz(ot * 16 + lrow, lk)];
        #pragma unroll
        for (int jt = 0; jt < 2; ++jt) obf[jt] = *(const short8*)&ob[(jt * 16 + lrow) * 40 + lk];
        #pragma unroll
        for (int ot = 0; ot < 4; ++ot) {
            int oc0 = ot * 16 + drow;
            #pragma unroll
            for (int jt = 0; jt < 2; ++jt) {
                f32x4 acc = { bol[oc0], bol[oc0 + 1], bol[oc0 + 2], bol[oc0 + 3] };
                acc = MFMA(wa[ot], obf[jt], acc);
                int jp = jt * 16 + lrow;
                *(ushort4*)&ao[(jp << 6) + (oc0 ^ ((jp & 7) << 3))] =
                    make_ushort4(f2bf(acc[0]), f2bf(acc[1]), f2bf(acc[2]), f2bf(acc[3]));
            }
        }
    }
    __syncthreads();   // BAR5: ao ready

    // ---- writer: out = x (f32, L3-hot re-read) + ao for c>=3 ----
    {
        const int wpx = t & 3, m = (t >> 2) & 31, cq = t >> 7;   // cq 0..1
        const uint16_t* aop = (const uint16_t*)(pool + wpx * ARENA_SZ) + 1320;
        const size_t obase = (((size_t)(b * 64 + cq * 32) * 32 + m) << 12) + (size_t)h * 64 + w0 + wpx;
        #pragma unroll
        for (int k = 0; k < 32; ++k) {
            int c = cq * 32 + k;
            float f = x[obase + (size_t)k * 131072];
            if (c >= 3) f += bf2f(aop[(m << 6) + ((c - 3) ^ ((m & 7) << 3))]);
            out[obase + (size_t)k * 131072] = f;
        }
    }
}

extern "C" void kernel_launch(void* const* d_in, const int* in_sizes, int n_in,
                              void* d_out, int out_size, void* d_ws, size_t ws_size,
                              hipStream_t stream) {
    const float* x     = (const float*)d_in[0];
    const float* light = (const float*)d_in[1];
    const float* wk  = (const float*)d_in[2];
    const float* bk  = (const float*)d_in[3];
    const float* wq  = (const float*)d_in[4];
    const float* bq  = (const float*)d_in[5];
    const float* wv  = (const float*)d_in[6];
    const float* bv  = (const float*)d_in[7];
    const float* wo  = (const float*)d_in[8];
    const float* bo  = (const float*)d_in[9];
    const float* lw1 = (const float*)d_in[10];
    const float* lb1 = (const float*)d_in[11];
    const float* lw2 = (const float*)d_in[12];
    const float* lb2 = (const float*)d_in[13];
    const float* lw3 = (const float*)d_in[14];
    const float* lb3 = (const float*)d_in[15];
    float* out   = (float*)d_out;
    uint16_t* le = (uint16_t*)d_ws;   // 4*33*33*32 bf16 = 278 KB

    light_emb_kernel<<<dim3((4 * 33 * 33 + 255) / 256), dim3(256), 0, stream>>>(
        light, lw1, lb1, lw2, lb2, lw3, lb3, le);
    fused_attn_kernel<<<dim3(4096), dim3(TB), 0, stream>>>(
        x, wk, bk, wq, bq, wv, bv, wo, bo, le, out);
}

// Round 10
// 196.214 us; speedup vs baseline: 1.2198x; 1.2198x over previous
//
#include <hip/hip_runtime.h>
#include <stdint.h>

#define TB 512
#define SCALE 0.17677669529663687f  // 1/sqrt(32)

typedef __attribute__((ext_vector_type(8))) short short8;
typedef __attribute__((ext_vector_type(4))) float f32x4;
#define MFMA(a, b, c) __builtin_amdgcn_mfma_f32_16x16x32_bf16(a, b, c, 0, 0, 0)

__device__ __forceinline__ float bf2f(uint16_t u) {
    union { uint32_t i; float f; } v; v.i = ((uint32_t)u) << 16; return v.f;
}
__device__ __forceinline__ uint16_t f2bf(float f) {
    union { float f; uint32_t i; } v; v.f = f;
    uint32_t r = v.i + 0x7fffu + ((v.i >> 16) & 1u);
    return (uint16_t)(r >> 16);
}
// xs: row n, channel c, stride 64 with 8-chunk XOR swizzle
__device__ __forceinline__ int swz(int n, int c)  { return (n << 6) + (c ^ ((n & 7) << 3)); }
// wol: row oc (64), s (32)
__device__ __forceinline__ int oswz(int oc, int s){ return (oc << 5) + (s ^ ((oc & 3) << 3)); }

// ---------------- K1: light positional embedding -> le[b][i][j][s] (bf16) ----------------
__global__ void light_emb_kernel(const float* __restrict__ light,
                                 const float* __restrict__ lw1, const float* __restrict__ lb1,
                                 const float* __restrict__ lw2, const float* __restrict__ lb2,
                                 const float* __restrict__ lw3, const float* __restrict__ lb3,
                                 uint16_t* __restrict__ le) {
    int e = blockIdx.x * 256 + threadIdx.x;
    if (e >= 4 * 33 * 33) return;
    int j = e % 33;
    int i = (e / 33) % 33;
    int b = e / (33 * 33);
    float d[3];
    #pragma unroll
    for (int c = 0; c < 3; ++c) {
        float a  = (i < 32) ? light[(b * 3 + c) * 32 + i] : -1.0f;
        float bb = (j < 32) ? light[(b * 3 + c) * 32 + j] : -1.0f;
        d[c] = a - bb;
    }
    float h1[8];
    #pragma unroll
    for (int o = 0; o < 8; ++o) {
        float s = lb1[o];
        #pragma unroll
        for (int c = 0; c < 3; ++c) s += lw1[o * 3 + c] * d[c];
        h1[o] = (s >= 0.f) ? s : 0.1f * s;
    }
    float h2[16];
    #pragma unroll
    for (int o = 0; o < 16; ++o) {
        float s = lb2[o];
        #pragma unroll
        for (int c = 0; c < 8; ++c) s += lw2[o * 8 + c] * h1[c];
        h2[o] = (s >= 0.f) ? s : 0.1f * s;
    }
    uint16_t* dst = le + (size_t)e * 32;
    #pragma unroll
    for (int o = 0; o < 32; ++o) {
        float s = lb3[o];
        #pragma unroll
        for (int c = 0; c < 16; ++c) s += lw3[o * 16 + c] * h2[c];
        dst[o] = f2bf(s);
    }
}

// LDS pool. Arenas (8 x 7840 = 62720) alias xs (264 rows x 128B = 33792 <= 62720).
// Per-pixel arena: [0,2640) kT -> sc -> abf -> ob ; [2640,5280) qT -> ao(stride 64)
//                  [5280,7840) v2
#define ARENA_SZ 7840
#define WOL_OFF  62720   // [64][32] bf16 swizzled = 4096
#define BIAS_OFF 66816   // f32[96]
#define BOL_OFF  67200   // f32[64]
#define POOL_SZ  67456   // 65.9 KB -> 2 blocks/CU

__global__ void __launch_bounds__(TB, 4)
fused_attn_kernel(const float* __restrict__ x,
                  const float* __restrict__ wk, const float* __restrict__ bk,
                  const float* __restrict__ wq, const float* __restrict__ bq,
                  const float* __restrict__ wv, const float* __restrict__ bv,
                  const float* __restrict__ wo, const float* __restrict__ bo,
                  const uint16_t* __restrict__ le,
                  float* __restrict__ out) {
    __shared__ __align__(16) unsigned char pool[POOL_SZ];
    uint16_t* xs   = (uint16_t*)pool;
    uint16_t* wol  = (uint16_t*)(pool + WOL_OFF);
    float*    bias = (float*)(pool + BIAS_OFF);
    float*    bol  = (float*)(pool + BOL_OFF);

    const int t = threadIdx.x;
    // XCD swizzle: the 8 w-tiles of one (b,h) land on the same XCD, adjacent in dispatch
    const int i_  = blockIdx.x;
    const int w0  = ((i_ >> 3) & 7) << 3;
    const int bh  = ((i_ >> 6) << 3) | (i_ & 7);
    const int b   = bh >> 6;
    const int h   = bh & 63;

    const int lane = t & 63, px = t >> 6;      // wave == pixel (8 waves)
    const int lrow = lane & 15;
    const int lk   = (lane >> 4) << 3;          // k-chunk base (8 bf16)
    const int drow = (lane >> 4) << 2;          // D-row base

    uint16_t* kT = (uint16_t*)(pool + px * ARENA_SZ);   // later sc/abf/ob
    uint16_t* qT = kT + 1320;                           // +2640 B; later ao
    uint16_t* v2 = kT + 2640;                           // +5280 B
    uint16_t* ao = qT;

    // ---- A-frags: projection weights straight from global (L2-hot) ----
    short8 af[6][2];
    {
        const float* wsel[3] = { wk, wq, wv };
        #pragma unroll
        for (int mt = 0; mt < 6; ++mt) {
            const float* wp = wsel[mt >> 1] + ((mt & 1) * 16 + lrow) * 64;
            #pragma unroll
            for (int hf = 0; hf < 2; ++hf) {
                float4 lo = *(const float4*)&wp[hf * 32 + lk];
                float4 hi = *(const float4*)&wp[hf * 32 + lk + 4];
                short8 v;
                v[0] = f2bf(lo.x); v[1] = f2bf(lo.y); v[2] = f2bf(lo.z); v[3] = f2bf(lo.w);
                v[4] = f2bf(hi.x); v[5] = f2bf(hi.y); v[6] = f2bf(hi.z); v[7] = f2bf(hi.w);
                af[mt][hf] = v;
            }
        }
    }

    // ---- P0: stage bias/bol/wol + x -> xs (bf16, swizzled, ushort4-packed) ----
    if (t < 96) bias[t] = (t < 32) ? bk[t] : (t < 64) ? bq[t - 32] : bv[t - 64];
    if (t < 64) bol[t] = (t < 61) ? bo[t] : 0.f;
    {
        // one ushort4 unit per thread: oc = t>>3, s0 = (t&7)*4
        int oc = t >> 3, s0 = (t & 7) * 4;
        ushort4 pk = make_ushort4(0, 0, 0, 0);
        if (oc < 61) {
            float4 wv4 = *(const float4*)&wo[oc * 32 + s0];
            pk = make_ushort4(f2bf(wv4.x), f2bf(wv4.y), f2bf(wv4.z), f2bf(wv4.w));
        }
        *(ushort4*)&wol[(oc << 5) + (s0 ^ ((oc & 3) << 3))] = pk;
    }
    #pragma unroll
    for (int u = 0; u < 2; ++u) {
        int unit = t + u * TB;              // (cg, m, fh): 1024 units
        int fh = unit & 1, m = (unit >> 1) & 31, cg = unit >> 6;
        int c0 = cg * 4;
        float4 xv[4];
        #pragma unroll
        for (int i = 0; i < 4; ++i)
            xv[i] = *(const float4*)&x[(((size_t)(b * 64 + c0 + i) * 32 + m) * 64 + h) * 64 + w0 + fh * 4];
        #pragma unroll
        for (int p = 0; p < 4; ++p) {
            int pxx = fh * 4 + p;
            ushort4 pk = make_ushort4(f2bf(((const float*)&xv[0])[p]),
                                      f2bf(((const float*)&xv[1])[p]),
                                      f2bf(((const float*)&xv[2])[p]),
                                      f2bf(((const float*)&xv[3])[p]));
            *(ushort4*)&xs[swz(pxx * 33 + m + 1, c0)] = pk;
        }
    }
    __syncthreads();   // BAR1: xs + wol + bias staged

    // ---- A2: extra token (m=0) = max over m=1..32 (own pixel) ----
    {
        const int c = lane;
        float mx = bf2f(xs[swz(px * 33 + 1, c)]);
        #pragma unroll
        for (int m = 2; m <= 32; ++m) mx = fmaxf(mx, bf2f(xs[swz(px * 33 + m, c)]));
        xs[swz(px * 33, c)] = f2bf(mx);
    }

    // ---- B-frags from xs (xs dies after this) ----
    short8 bfr[3][2];
    #pragma unroll
    for (int nt = 0; nt < 3; ++nt) {
        int n = px * 33 + nt * 16 + lrow;   // may read garbage rows (discarded)
        bfr[nt][0] = *(const short8*)&xs[swz(n, lk)];
        bfr[nt][1] = *(const short8*)&xs[swz(n, 32 + lk)];
    }
    __syncthreads();   // BAR2: frags in regs; arenas may overwrite xs

    // ---- B: projections. D[q][m] = W[q][c] * xs[m][c]^T + bias ----
    #pragma unroll
    for (int mt = 0; mt < 6; ++mt) {
        int q0 = mt * 16 + drow;
        #pragma unroll
        for (int nt = 0; nt < 3; ++nt) {
            f32x4 acc = { bias[q0], bias[q0 + 1], bias[q0 + 2], bias[q0 + 3] };
            acc = MFMA(af[mt][0], bfr[nt][0], acc);
            acc = MFMA(af[mt][1], bfr[nt][1], acc);
            int m = nt * 16 + lrow;
            if (m <= 32) {
                if (q0 < 32) {
                    *(ushort4*)&kT[m * 40 + q0] =
                        make_ushort4(f2bf(acc[0]), f2bf(acc[1]), f2bf(acc[2]), f2bf(acc[3]));
                } else if (q0 < 64) {
                    *(ushort4*)&qT[m * 40 + (q0 - 32)] =
                        make_ushort4(f2bf(acc[0]), f2bf(acc[1]), f2bf(acc[2]), f2bf(acc[3]));
                } else {
                    #pragma unroll
                    for (int r = 0; r < 4; ++r)
                        v2[(q0 - 64 + r) * 40 + m] = f2bf(acc[r]);
                }
            }
        }
    }

    // ---- C1: raw scores sc[jp][i] (bf16, overwrites kT after reads) ----
    {
        short8 ka[3], qb[2];
        #pragma unroll
        for (int mt = 0; mt < 3; ++mt) ka[mt] = *(const short8*)&kT[(mt * 16 + lrow) * 40 + lk];
        #pragma unroll
        for (int jh = 0; jh < 2; ++jh) qb[jh] = *(const short8*)&qT[(1 + jh * 16 + lrow) * 40 + lk];
        f32x4 sa[3][2];
        #pragma unroll
        for (int mt = 0; mt < 3; ++mt)
            #pragma unroll
            for (int jh = 0; jh < 2; ++jh) {
                f32x4 z = { 0.f, 0.f, 0.f, 0.f };
                sa[mt][jh] = MFMA(ka[mt], qb[jh], z);
            }
        uint16_t* sc = kT;
        #pragma unroll
        for (int jh = 0; jh < 2; ++jh) {
            int jp = jh * 16 + lrow;
            #pragma unroll
            for (int mt = 0; mt < 2; ++mt) {
                int i0 = mt * 16 + drow;
                *(ushort4*)&sc[jp * 40 + i0] =
                    make_ushort4(f2bf(sa[mt][jh][0]), f2bf(sa[mt][jh][1]),
                                 f2bf(sa[mt][jh][2]), f2bf(sa[mt][jh][3]));
            }
            if (drow == 0) sc[jp * 40 + 32] = f2bf(sa[2][jh][0]);
        }
    }

    // ---- le prefetch (T14): issue global loads; latency hides under softmax ----
    short8 le0[4], le1[4];
    short8 le0e = {}, le1e = {};
    {
        const uint16_t* leb = le + (size_t)b * (33 * 33 * 32);
        #pragma unroll
        for (int qi = 0; qi < 4; ++qi) {
            int k = px * 4 + qi;
            le0[qi] = *(const short8*)&leb[(k * 33 + 1 + lrow) * 32 + lk];
            le1[qi] = *(const short8*)&leb[(k * 33 + 17 + lrow) * 32 + lk];
        }
        if (px == 0) {
            le0e = *(const short8*)&leb[(32 * 33 + 1 + lrow) * 32 + lk];
            le1e = *(const short8*)&leb[(32 * 33 + 17 + lrow) * 32 + lk];
        }
    }

    // ---- C2a: softmax over i per column jp (lane halves split i, shfl combine) ----
    {
        uint16_t* sc = kT;
        const int jp = lane & 31, hi = lane >> 5;
        const int ib = hi ? 16 : 0;
        float v[17];
        #pragma unroll
        for (int g = 0; g < 4; ++g) {
            ushort4 u = *(const ushort4*)&sc[jp * 40 + ib + g * 4];
            v[g * 4 + 0] = bf2f(u.x); v[g * 4 + 1] = bf2f(u.y);
            v[g * 4 + 2] = bf2f(u.z); v[g * 4 + 3] = bf2f(u.w);
        }
        if (hi) v[16] = bf2f(sc[jp * 40 + 32]);
        float mx = v[0];
        #pragma unroll
        for (int k = 1; k < 16; ++k) mx = fmaxf(mx, v[k]);
        if (hi) mx = fmaxf(mx, v[16]);
        mx = fmaxf(mx, __shfl_xor(mx, 32, 64));
        float sum = 0.f;
        #pragma unroll
        for (int k = 0; k < 16; ++k) { v[k] = __expf((v[k] - mx) * SCALE); sum += v[k]; }
        if (hi) { v[16] = __expf((v[16] - mx) * SCALE); sum += v[16]; }
        sum += __shfl_xor(sum, 32, 64);
        float r = 1.0f / sum;
        #pragma unroll
        for (int g = 0; g < 4; ++g) {
            *(ushort4*)&sc[jp * 40 + ib + g * 4] =
                make_ushort4(f2bf(v[g * 4 + 0] * r), f2bf(v[g * 4 + 1] * r),
                             f2bf(v[g * 4 + 2] * r), f2bf(v[g * 4 + 3] * r));
        }
        if (hi) sc[jp * 40 + 32] = f2bf(v[16] * r);
    }
    __syncthreads();   // BAR3: all sc + qT stable

    // ---- C2b (block-coop): per key-row k, bias[px][j] = sum_s q[px][s][k]*le[s][k][j]
    //      one MFMA covers all 8 pixels; wave px owns k = 4*px..4*px+3 (+32 on wave 0)
    {
        const int pxs = lrow & 7;
        const uint16_t* qsrc = (const uint16_t*)(pool + pxs * ARENA_SZ) + 1320;
        #pragma unroll
        for (int qi = 0; qi < 4; ++qi) {
            int k = px * 4 + qi;
            short8 aq = *(const short8*)&qsrc[k * 40 + lk];
            f32x4 z = { 0.f, 0.f, 0.f, 0.f };
            f32x4 r0 = MFMA(aq, le0[qi], z);
            f32x4 r1 = MFMA(aq, le1[qi], z);
            if (lane < 32) {
                #pragma unroll
                for (int r = 0; r < 4; ++r) {
                    int pxd = drow + r;   // 0..7
                    uint16_t* scp = (uint16_t*)(pool + pxd * ARENA_SZ);
                    int o0 = lrow * 40 + k, o1 = (16 + lrow) * 40 + k;
                    scp[o0] = f2bf(bf2f(scp[o0]) + r0[r]);
                    scp[o1] = f2bf(bf2f(scp[o1]) + r1[r]);
                }
            }
        }
        if (px == 0) {
            const int k = 32;
            short8 aq = *(const short8*)&qsrc[k * 40 + lk];
            f32x4 z = { 0.f, 0.f, 0.f, 0.f };
            f32x4 r0 = MFMA(aq, le0e, z);
            f32x4 r1 = MFMA(aq, le1e, z);
            if (lane < 32) {
                #pragma unroll
                for (int r = 0; r < 4; ++r) {
                    int pxd = drow + r;
                    uint16_t* scp = (uint16_t*)(pool + pxd * ARENA_SZ);
                    int o0 = lrow * 40 + k, o1 = (16 + lrow) * 40 + k;
                    scp[o0] = f2bf(bf2f(scp[o0]) + r0[r]);
                    scp[o1] = f2bf(bf2f(scp[o1]) + r1[r]);
                }
            }
        }
    }
    __syncthreads();   // BAR4: bias applied, qT free

    // ---- writer x prefetch (first half): hides L2/L3 latency under C3+D ----
    const int wpx = t & 7, wm = (t >> 3) & 31, cq = t >> 8;   // cq 0..1
    const size_t obase = (((size_t)(b * 64 + cq * 32) * 32 + wm) << 12) + (size_t)h * 64 + w0 + wpx;
    float xpre[16];
    #pragma unroll
    for (int k = 0; k < 16; ++k) xpre[k] = x[obase + (size_t)k * 131072];

    // ---- C3: o[s][jp] = sum_m v2[s][m]*a[jp][m] (+ m=32 tail); ob overwrites abf ----
    {
        uint16_t* abf = kT;
        short8 va[2], bb[2];
        #pragma unroll
        for (int st = 0; st < 2; ++st) va[st] = *(const short8*)&v2[(st * 16 + lrow) * 40 + lk];
        #pragma unroll
        for (int jt = 0; jt < 2; ++jt) bb[jt] = *(const short8*)&abf[(jt * 16 + lrow) * 40 + lk];
        f32x4 oacc[2][2];
        #pragma unroll
        for (int st = 0; st < 2; ++st)
            #pragma unroll
            for (int jt = 0; jt < 2; ++jt) {
                f32x4 z = { 0.f, 0.f, 0.f, 0.f };
                oacc[st][jt] = MFMA(va[st], bb[jt], z);
            }
        float a32[2], vt[2][4];
        #pragma unroll
        for (int jt = 0; jt < 2; ++jt) a32[jt] = bf2f(abf[(jt * 16 + lrow) * 40 + 32]);
        #pragma unroll
        for (int st = 0; st < 2; ++st)
            #pragma unroll
            for (int r = 0; r < 4; ++r) vt[st][r] = bf2f(v2[(st * 16 + drow + r) * 40 + 32]);
        uint16_t* ob = kT;
        #pragma unroll
        for (int st = 0; st < 2; ++st)
            #pragma unroll
            for (int jt = 0; jt < 2; ++jt) {
                #pragma unroll
                for (int r = 0; r < 4; ++r) oacc[st][jt][r] += vt[st][r] * a32[jt];
                int s0 = st * 16 + drow, jp = jt * 16 + lrow;
                *(ushort4*)&ob[jp * 40 + s0] =
                    make_ushort4(f2bf(oacc[st][jt][0]), f2bf(oacc[st][jt][1]),
                                 f2bf(oacc[st][jt][2]), f2bf(oacc[st][jt][3]));
            }
    }

    // ---- D: ao[jp][oc] = wo @ o + bo (ao overwrites qT, stride-64 swizzled) ----
    {
        uint16_t* ob = kT;
        short8 wa[4], obf[2];
        #pragma unroll
        for (int ot = 0; ot < 4; ++ot) wa[ot] = *(const short8*)&wol[oswz(ot * 16 + lrow, lk)];
        #pragma unroll
        for (int jt = 0; jt < 2; ++jt) obf[jt] = *(const short8*)&ob[(jt * 16 + lrow) * 40 + lk];
        #pragma unroll
        for (int ot = 0; ot < 4; ++ot) {
            int oc0 = ot * 16 + drow;
            #pragma unroll
            for (int jt = 0; jt < 2; ++jt) {
                f32x4 acc = { bol[oc0], bol[oc0 + 1], bol[oc0 + 2], bol[oc0 + 3] };
                acc = MFMA(wa[ot], obf[jt], acc);
                int jp = jt * 16 + lrow;
                *(ushort4*)&ao[(jp << 6) + (oc0 ^ ((jp & 7) << 3))] =
                    make_ushort4(f2bf(acc[0]), f2bf(acc[1]), f2bf(acc[2]), f2bf(acc[3]));
            }
        }
    }
    __syncthreads();   // BAR5: ao ready

    // ---- writer: out = x + ao (c>=3); ao read as short8 chunks, 32B stores ----
    {
        const uint16_t* aop = (const uint16_t*)(pool + wpx * ARENA_SZ) + 1320;
        const int cb = cq * 3;
        short8 av[5];
        #pragma unroll
        for (int i = 0; i < 5; ++i)
            av[i] = *(const short8*)&aop[(wm << 6) + ((((cb + i) << 3)) ^ ((wm & 7) << 3))];
        float xr[16];
        #pragma unroll
        for (int k = 0; k < 16; ++k) xr[k] = x[obase + (size_t)(16 + k) * 131072];
        #pragma unroll
        for (int k = 0; k < 32; ++k) {
            int c = cq * 32 + k;
            float f = (k < 16) ? xpre[k] : xr[k - 16];
            int oc = c - 3;
            if (oc >= 0) f += bf2f((uint16_t)av[(oc >> 3) - cb][oc & 7]);
            out[obase + (size_t)k * 131072] = f;
        }
    }
}

extern "C" void kernel_launch(void* const* d_in, const int* in_sizes, int n_in,
                              void* d_out, int out_size, void* d_ws, size_t ws_size,
                              hipStream_t stream) {
    const float* x     = (const float*)d_in[0];
    const float* light = (const float*)d_in[1];
    const float* wk  = (const float*)d_in[2];
    const float* bk  = (const float*)d_in[3];
    const float* wq  = (const float*)d_in[4];
    const float* bq  = (const float*)d_in[5];
    const float* wv  = (const float*)d_in[6];
    const float* bv  = (const float*)d_in[7];
    const float* wo  = (const float*)d_in[8];
    const float* bo  = (const float*)d_in[9];
    const float* lw1 = (const float*)d_in[10];
    const float* lb1 = (const float*)d_in[11];
    const float* lw2 = (const float*)d_in[12];
    const float* lb2 = (const float*)d_in[13];
    const float* lw3 = (const float*)d_in[14];
    const float* lb3 = (const float*)d_in[15];
    float* out   = (float*)d_out;
    uint16_t* le = (uint16_t*)d_ws;   // 4*33*33*32 bf16 = 278 KB

    light_emb_kernel<<<dim3((4 * 33 * 33 + 255) / 256), dim3(256), 0, stream>>>(
        light, lw1, lb1, lw2, lb2, lw3, lb3, le);
    fused_attn_kernel<<<dim3(2048), dim3(TB), 0, stream>>>(
        x, wk, bk, wq, bq, wv, bv, wo, bo, le, out);
}

// Round 11
// 106.403 us; speedup vs baseline: 2.2494x; 1.8441x over previous
//
#include <hip/hip_runtime.h>
#include <hip/hip_bf16.h>
#include <stdint.h>

#define TB 512
#define SCALE 0.17677669529663687f  // 1/sqrt(32)

typedef __attribute__((ext_vector_type(8))) short short8;
typedef __attribute__((ext_vector_type(4))) float f32x4;
#define MFMA(a, b, c) __builtin_amdgcn_mfma_f32_16x16x32_bf16(a, b, c, 0, 0, 0)

__device__ __forceinline__ float bf2f(uint16_t u) {
    union { uint32_t i; float f; } v; v.i = ((uint32_t)u) << 16; return v.f;
}
// native bf16 convert (RNE) — compiler picks the best gfx950 lowering (m240)
__device__ __forceinline__ uint16_t f2bf(float f) {
    __hip_bfloat16 h = __float2bfloat16(f);
    uint16_t u; __builtin_memcpy(&u, &h, 2); return u;
}
// xs: row n, channel c, stride 64 with 8-chunk XOR swizzle
__device__ __forceinline__ int swz(int n, int c)  { return (n << 6) + (c ^ ((n & 7) << 3)); }
// wbuf: row q (96), channel c (64)
__device__ __forceinline__ int wswz(int q, int c) { return (q << 6) + (c ^ ((q & 7) << 3)); }
// wol: row oc (64), s (32)
__device__ __forceinline__ int oswz(int oc, int s){ return (oc << 5) + (s ^ ((oc & 3) << 3)); }

// ---------------- K1: light positional embedding -> le[b][i][j][s] (bf16) ----------------
__global__ void light_emb_kernel(const float* __restrict__ light,
                                 const float* __restrict__ lw1, const float* __restrict__ lb1,
                                 const float* __restrict__ lw2, const float* __restrict__ lb2,
                                 const float* __restrict__ lw3, const float* __restrict__ lb3,
                                 uint16_t* __restrict__ le) {
    int e = blockIdx.x * 256 + threadIdx.x;
    if (e >= 4 * 33 * 33) return;
    int j = e % 33;
    int i = (e / 33) % 33;
    int b = e / (33 * 33);
    float d[3];
    #pragma unroll
    for (int c = 0; c < 3; ++c) {
        float a  = (i < 32) ? light[(b * 3 + c) * 32 + i] : -1.0f;
        float bb = (j < 32) ? light[(b * 3 + c) * 32 + j] : -1.0f;
        d[c] = a - bb;
    }
    float h1[8];
    #pragma unroll
    for (int o = 0; o < 8; ++o) {
        float s = lb1[o];
        #pragma unroll
        for (int c = 0; c < 3; ++c) s += lw1[o * 3 + c] * d[c];
        h1[o] = (s >= 0.f) ? s : 0.1f * s;
    }
    float h2[16];
    #pragma unroll
    for (int o = 0; o < 16; ++o) {
        float s = lb2[o];
        #pragma unroll
        for (int c = 0; c < 8; ++c) s += lw2[o * 8 + c] * h1[c];
        h2[o] = (s >= 0.f) ? s : 0.1f * s;
    }
    uint16_t* dst = le + (size_t)e * 32;
    #pragma unroll
    for (int o = 0; o < 32; ++o) {
        float s = lb3[o];
        #pragma unroll
        for (int c = 0; c < 16; ++c) s += lw3[o * 16 + c] * h2[c];
        dst[o] = f2bf(s);
    }
}

// LDS pool. Arenas (8 x 7840 = 62720) alias xs (264 rows x 128B = 33792 <= 62720).
// Per-pixel arena: [0,2640) kT -> sc -> abf -> ob ; [2640,5280) qT -> ao(stride 64)
//                  [5280,7840) v2
#define ARENA_SZ 7840
#define WBUF_OFF 62720   // [96][64] bf16 swizzled = 12288
#define WOL_OFF  75008   // [64][32] bf16 swizzled = 4096
#define BIAS_OFF 79104   // f32[96]
#define BOL_OFF  79488   // f32[64]
#define POOL_SZ  79744   // 77.9 KB -> 2 blocks/CU

__global__ void __launch_bounds__(TB, 4)
fused_attn_kernel(const float* __restrict__ x,
                  const float* __restrict__ wk, const float* __restrict__ bk,
                  const float* __restrict__ wq, const float* __restrict__ bq,
                  const float* __restrict__ wv, const float* __restrict__ bv,
                  const float* __restrict__ wo, const float* __restrict__ bo,
                  const uint16_t* __restrict__ le,
                  float* __restrict__ out) {
    __shared__ __align__(16) unsigned char pool[POOL_SZ];
    uint16_t* xs   = (uint16_t*)pool;
    uint16_t* wbuf = (uint16_t*)(pool + WBUF_OFF);
    uint16_t* wol  = (uint16_t*)(pool + WOL_OFF);
    float*    bias = (float*)(pool + BIAS_OFF);
    float*    bol  = (float*)(pool + BOL_OFF);

    const int t = threadIdx.x;
    // XCD swizzle: the 8 w-tiles of one (b,h) land on the same XCD, adjacent in dispatch
    const int i_  = blockIdx.x;
    const int w0  = ((i_ >> 3) & 7) << 3;
    const int bh  = ((i_ >> 6) << 3) | (i_ & 7);
    const int b   = bh >> 6;
    const int h   = bh & 63;

    const int lane = t & 63, px = t >> 6;      // wave == pixel (8 waves)
    const int lrow = lane & 15;
    const int lk   = (lane >> 4) << 3;          // k-chunk base (8 bf16)
    const int drow = (lane >> 4) << 2;          // D-row base

    uint16_t* kT = (uint16_t*)(pool + px * ARENA_SZ);   // later sc/abf/ob
    uint16_t* qT = kT + 1320;                           // +2640 B; later ao
    uint16_t* v2 = kT + 2640;                           // +5280 B
    uint16_t* ao = qT;

    // ---- P0: stage wbuf/bias/wol/bol + x -> xs (all bf16, vectorized) ----
    #pragma unroll
    for (int u = 0; u < 3; ++u) {
        int e = t + u * TB;                 // 1536 ushort4 units = 96 q x 16 cg
        int q = e >> 4, c0 = (e & 15) * 4;
        const float* wp = (q < 32) ? &wk[q * 64 + c0]
                        : (q < 64) ? &wq[(q - 32) * 64 + c0]
                                   : &wv[(q - 64) * 64 + c0];
        float4 wv4 = *(const float4*)wp;
        *(ushort4*)&wbuf[(q << 6) + (c0 ^ ((q & 7) << 3))] =
            make_ushort4(f2bf(wv4.x), f2bf(wv4.y), f2bf(wv4.z), f2bf(wv4.w));
    }
    if (t < 96) bias[t] = (t < 32) ? bk[t] : (t < 64) ? bq[t - 32] : bv[t - 64];
    if (t < 64) bol[t] = (t < 61) ? bo[t] : 0.f;
    {
        int oc = t >> 3, s0 = (t & 7) * 4;
        ushort4 pk = make_ushort4(0, 0, 0, 0);
        if (oc < 61) {
            float4 wv4 = *(const float4*)&wo[oc * 32 + s0];
            pk = make_ushort4(f2bf(wv4.x), f2bf(wv4.y), f2bf(wv4.z), f2bf(wv4.w));
        }
        *(ushort4*)&wol[(oc << 5) + (s0 ^ ((oc & 3) << 3))] = pk;
    }
    #pragma unroll
    for (int u = 0; u < 2; ++u) {
        int unit = t + u * TB;              // (cg, m, fh): 1024 units
        int fh = unit & 1, m = (unit >> 1) & 31, cg = unit >> 6;
        int c0 = cg * 4;
        float4 xv[4];
        #pragma unroll
        for (int i = 0; i < 4; ++i)
            xv[i] = *(const float4*)&x[(((size_t)(b * 64 + c0 + i) * 32 + m) * 64 + h) * 64 + w0 + fh * 4];
        #pragma unroll
        for (int p = 0; p < 4; ++p) {
            int pxx = fh * 4 + p;
            ushort4 pk = make_ushort4(f2bf(((const float*)&xv[0])[p]),
                                      f2bf(((const float*)&xv[1])[p]),
                                      f2bf(((const float*)&xv[2])[p]),
                                      f2bf(((const float*)&xv[3])[p]));
            *(ushort4*)&xs[swz(pxx * 33 + m + 1, c0)] = pk;
        }
    }
    __syncthreads();   // BAR1: xs + weights staged

    // ---- A2: extra token (m=0) = max over m=1..32 (own pixel) ----
    {
        const int c = lane;
        float mx = bf2f(xs[swz(px * 33 + 1, c)]);
        #pragma unroll
        for (int m = 2; m <= 32; ++m) mx = fmaxf(mx, bf2f(xs[swz(px * 33 + m, c)]));
        xs[swz(px * 33, c)] = f2bf(mx);
    }

    // ---- load proj fragments into registers (xs dies after this) ----
    short8 af[6][2], bfr[3][2];
    #pragma unroll
    for (int mt = 0; mt < 6; ++mt) {
        af[mt][0] = *(const short8*)&wbuf[wswz(mt * 16 + lrow, lk)];
        af[mt][1] = *(const short8*)&wbuf[wswz(mt * 16 + lrow, 32 + lk)];
    }
    #pragma unroll
    for (int nt = 0; nt < 3; ++nt) {
        int n = px * 33 + nt * 16 + lrow;   // may read garbage rows (discarded)
        bfr[nt][0] = *(const short8*)&xs[swz(n, lk)];
        bfr[nt][1] = *(const short8*)&xs[swz(n, 32 + lk)];
    }
    __syncthreads();   // BAR2: frags in regs; arenas may overwrite xs

    // ---- B: projections. D[q][m] = W[q][c] * xs[m][c]^T + bias ----
    #pragma unroll
    for (int mt = 0; mt < 6; ++mt) {
        int q0 = mt * 16 + drow;
        #pragma unroll
        for (int nt = 0; nt < 3; ++nt) {
            f32x4 acc = { bias[q0], bias[q0 + 1], bias[q0 + 2], bias[q0 + 3] };
            acc = MFMA(af[mt][0], bfr[nt][0], acc);
            acc = MFMA(af[mt][1], bfr[nt][1], acc);
            int m = nt * 16 + lrow;
            if (m <= 32) {
                if (q0 < 32) {
                    *(ushort4*)&kT[m * 40 + q0] =
                        make_ushort4(f2bf(acc[0]), f2bf(acc[1]), f2bf(acc[2]), f2bf(acc[3]));
                } else if (q0 < 64) {
                    *(ushort4*)&qT[m * 40 + (q0 - 32)] =
                        make_ushort4(f2bf(acc[0]), f2bf(acc[1]), f2bf(acc[2]), f2bf(acc[3]));
                } else {
                    #pragma unroll
                    for (int r = 0; r < 4; ++r)
                        v2[(q0 - 64 + r) * 40 + m] = f2bf(acc[r]);
                }
            }
        }
    }

    // ---- C1: raw scores sc[jp][i] (bf16, overwrites kT after reads) ----
    {
        short8 ka[3], qb[2];
        #pragma unroll
        for (int mt = 0; mt < 3; ++mt) ka[mt] = *(const short8*)&kT[(mt * 16 + lrow) * 40 + lk];
        #pragma unroll
        for (int jh = 0; jh < 2; ++jh) qb[jh] = *(const short8*)&qT[(1 + jh * 16 + lrow) * 40 + lk];
        f32x4 sa[3][2];
        #pragma unroll
        for (int mt = 0; mt < 3; ++mt)
            #pragma unroll
            for (int jh = 0; jh < 2; ++jh) {
                f32x4 z = { 0.f, 0.f, 0.f, 0.f };
                sa[mt][jh] = MFMA(ka[mt], qb[jh], z);
            }
        uint16_t* sc = kT;
        #pragma unroll
        for (int jh = 0; jh < 2; ++jh) {
            int jp = jh * 16 + lrow;
            #pragma unroll
            for (int mt = 0; mt < 2; ++mt) {
                int i0 = mt * 16 + drow;
                *(ushort4*)&sc[jp * 40 + i0] =
                    make_ushort4(f2bf(sa[mt][jh][0]), f2bf(sa[mt][jh][1]),
                                 f2bf(sa[mt][jh][2]), f2bf(sa[mt][jh][3]));
            }
            if (drow == 0) sc[jp * 40 + 32] = f2bf(sa[2][jh][0]);
        }
    }

    // ---- le prefetch (T14): global loads issued here, hide under softmax ----
    short8 le0[4], le1[4];
    short8 le0e = {}, le1e = {};
    {
        const uint16_t* leb = le + (size_t)b * (33 * 33 * 32);
        #pragma unroll
        for (int qi = 0; qi < 4; ++qi) {
            int k = px * 4 + qi;
            le0[qi] = *(const short8*)&leb[(k * 33 + 1 + lrow) * 32 + lk];
            le1[qi] = *(const short8*)&leb[(k * 33 + 17 + lrow) * 32 + lk];
        }
        if (px == 0) {
            le0e = *(const short8*)&leb[(32 * 33 + 1 + lrow) * 32 + lk];
            le1e = *(const short8*)&leb[(32 * 33 + 17 + lrow) * 32 + lk];
        }
    }

    // ---- C2a: softmax over i per column jp (lane halves split i, shfl combine) ----
    {
        uint16_t* sc = kT;
        const int jp = lane & 31, hi = lane >> 5;
        const int ib = hi ? 16 : 0;
        float v[17];
        #pragma unroll
        for (int g = 0; g < 4; ++g) {
            ushort4 u = *(const ushort4*)&sc[jp * 40 + ib + g * 4];
            v[g * 4 + 0] = bf2f(u.x); v[g * 4 + 1] = bf2f(u.y);
            v[g * 4 + 2] = bf2f(u.z); v[g * 4 + 3] = bf2f(u.w);
        }
        if (hi) v[16] = bf2f(sc[jp * 40 + 32]);
        float mx = v[0];
        #pragma unroll
        for (int k = 1; k < 16; ++k) mx = fmaxf(mx, v[k]);
        if (hi) mx = fmaxf(mx, v[16]);
        mx = fmaxf(mx, __shfl_xor(mx, 32, 64));
        float sum = 0.f;
        #pragma unroll
        for (int k = 0; k < 16; ++k) { v[k] = __expf((v[k] - mx) * SCALE); sum += v[k]; }
        if (hi) { v[16] = __expf((v[16] - mx) * SCALE); sum += v[16]; }
        sum += __shfl_xor(sum, 32, 64);
        float r = 1.0f / sum;
        #pragma unroll
        for (int g = 0; g < 4; ++g) {
            *(ushort4*)&sc[jp * 40 + ib + g * 4] =
                make_ushort4(f2bf(v[g * 4 + 0] * r), f2bf(v[g * 4 + 1] * r),
                             f2bf(v[g * 4 + 2] * r), f2bf(v[g * 4 + 3] * r));
        }
        if (hi) sc[jp * 40 + 32] = f2bf(v[16] * r);
    }
    __syncthreads();   // BAR3: all sc + qT stable

    // ---- C2b (block-coop): per key-row k, bias[px][j] = sum_s q[px][s][k]*le[s][k][j]
    //      one MFMA covers all 8 pixels; wave px owns k = 4*px..4*px+3 (+32 on wave 0)
    {
        const int pxs = lrow & 7;
        const uint16_t* qsrc = (const uint16_t*)(pool + pxs * ARENA_SZ) + 1320;
        #pragma unroll
        for (int qi = 0; qi < 4; ++qi) {
            int k = px * 4 + qi;
            short8 aq = *(const short8*)&qsrc[k * 40 + lk];
            f32x4 z = { 0.f, 0.f, 0.f, 0.f };
            f32x4 r0 = MFMA(aq, le0[qi], z);
            f32x4 r1 = MFMA(aq, le1[qi], z);
            if (lane < 32) {
                #pragma unroll
                for (int r = 0; r < 4; ++r) {
                    int pxd = drow + r;   // 0..7
                    uint16_t* scp = (uint16_t*)(pool + pxd * ARENA_SZ);
                    int o0 = lrow * 40 + k, o1 = (16 + lrow) * 40 + k;
                    scp[o0] = f2bf(bf2f(scp[o0]) + r0[r]);
                    scp[o1] = f2bf(bf2f(scp[o1]) + r1[r]);
                }
            }
        }
        if (px == 0) {
            const int k = 32;
            short8 aq = *(const short8*)&qsrc[k * 40 + lk];
            f32x4 z = { 0.f, 0.f, 0.f, 0.f };
            f32x4 r0 = MFMA(aq, le0e, z);
            f32x4 r1 = MFMA(aq, le1e, z);
            if (lane < 32) {
                #pragma unroll
                for (int r = 0; r < 4; ++r) {
                    int pxd = drow + r;
                    uint16_t* scp = (uint16_t*)(pool + pxd * ARENA_SZ);
                    int o0 = lrow * 40 + k, o1 = (16 + lrow) * 40 + k;
                    scp[o0] = f2bf(bf2f(scp[o0]) + r0[r]);
                    scp[o1] = f2bf(bf2f(scp[o1]) + r1[r]);
                }
            }
        }
    }
    __syncthreads();   // BAR4: bias applied, qT free

    // ---- C3: o[s][jp] = sum_m v2[s][m]*a[jp][m] (+ m=32 tail); ob overwrites abf ----
    {
        uint16_t* abf = kT;
        short8 va[2], bb[2];
        #pragma unroll
        for (int st = 0; st < 2; ++st) va[st] = *(const short8*)&v2[(st * 16 + lrow) * 40 + lk];
        #pragma unroll
        for (int jt = 0; jt < 2; ++jt) bb[jt] = *(const short8*)&abf[(jt * 16 + lrow) * 40 + lk];
        f32x4 oacc[2][2];
        #pragma unroll
        for (int st = 0; st < 2; ++st)
            #pragma unroll
            for (int jt = 0; jt < 2; ++jt) {
                f32x4 z = { 0.f, 0.f, 0.f, 0.f };
                oacc[st][jt] = MFMA(va[st], bb[jt], z);
            }
        float a32[2], vt[2][4];
        #pragma unroll
        for (int jt = 0; jt < 2; ++jt) a32[jt] = bf2f(abf[(jt * 16 + lrow) * 40 + 32]);
        #pragma unroll
        for (int st = 0; st < 2; ++st)
            #pragma unroll
            for (int r = 0; r < 4; ++r) vt[st][r] = bf2f(v2[(st * 16 + drow + r) * 40 + 32]);
        uint16_t* ob = kT;
        #pragma unroll
        for (int st = 0; st < 2; ++st)
            #pragma unroll
            for (int jt = 0; jt < 2; ++jt) {
                #pragma unroll
                for (int r = 0; r < 4; ++r) oacc[st][jt][r] += vt[st][r] * a32[jt];
                int s0 = st * 16 + drow, jp = jt * 16 + lrow;
                *(ushort4*)&ob[jp * 40 + s0] =
                    make_ushort4(f2bf(oacc[st][jt][0]), f2bf(oacc[st][jt][1]),
                                 f2bf(oacc[st][jt][2]), f2bf(oacc[st][jt][3]));
            }
    }

    // ---- D: ao[jp][oc] = wo @ o + bo (ao overwrites qT, stride-64 swizzled) ----
    {
        uint16_t* ob = kT;
        short8 wa[4], obf[2];
        #pragma unroll
        for (int ot = 0; ot < 4; ++ot) wa[ot] = *(const short8*)&wol[oswz(ot * 16 + lrow, lk)];
        #pragma unroll
        for (int jt = 0; jt < 2; ++jt) obf[jt] = *(const short8*)&ob[(jt * 16 + lrow) * 40 + lk];
        #pragma unroll
        for (int ot = 0; ot < 4; ++ot) {
            int oc0 = ot * 16 + drow;
            #pragma unroll
            for (int jt = 0; jt < 2; ++jt) {
                f32x4 acc = { bol[oc0], bol[oc0 + 1], bol[oc0 + 2], bol[oc0 + 3] };
                acc = MFMA(wa[ot], obf[jt], acc);
                int jp = jt * 16 + lrow;
                *(ushort4*)&ao[(jp << 6) + (oc0 ^ ((jp & 7) << 3))] =
                    make_ushort4(f2bf(acc[0]), f2bf(acc[1]), f2bf(acc[2]), f2bf(acc[3]));
            }
        }
    }
    __syncthreads();   // BAR5: ao ready

    // ---- writer: out = x + ao (c>=3); ao via b128 reads, constant vector indexing ----
    {
        const int wpx = t & 7, wm = (t >> 3) & 31, cq = t >> 8;   // cq wave-uniform
        const uint16_t* aop = (const uint16_t*)(pool + wpx * ARENA_SZ) + 1320;
        const int wm6 = wm << 6, wx = (wm & 7) << 3;
        const size_t obase = (((size_t)(b * 64 + cq * 32) * 32 + wm) << 12) + (size_t)h * 64 + w0 + wpx;
#define LDA(i)  (*(const short8*)&aop[wm6 + (((i) << 3) ^ wx)])
#define W0(k)   { out[obase + (size_t)(k) * 131072] = x[obase + (size_t)(k) * 131072]; }
#define WA(k, av, j) { out[obase + (size_t)(k) * 131072] = \
                       x[obase + (size_t)(k) * 131072] + bf2f((uint16_t)(av)[j]); }
#define WA8(k0, av) WA(k0, av, 0) WA((k0)+1, av, 1) WA((k0)+2, av, 2) WA((k0)+3, av, 3) \
                    WA((k0)+4, av, 4) WA((k0)+5, av, 5) WA((k0)+6, av, 6) WA((k0)+7, av, 7)
        if (cq == 0) {
            short8 a0 = LDA(0), a1 = LDA(1), a2 = LDA(2), a3 = LDA(3);
            W0(0) W0(1) W0(2)
            WA8(3, a0) WA8(11, a1) WA8(19, a2)
            WA(27, a3, 0) WA(28, a3, 1) WA(29, a3, 2) WA(30, a3, 3) WA(31, a3, 4)
        } else {
            short8 a3 = LDA(3), a4 = LDA(4), a5 = LDA(5), a6 = LDA(6), a7 = LDA(7);
            WA(0, a3, 5) WA(1, a3, 6) WA(2, a3, 7)
            WA8(3, a4) WA8(11, a5) WA8(19, a6)
            WA(27, a7, 0) WA(28, a7, 1) WA(29, a7, 2) WA(30, a7, 3) WA(31, a7, 4)
        }
#undef LDA
#undef W0
#undef WA
#undef WA8
    }
}

extern "C" void kernel_launch(void* const* d_in, const int* in_sizes, int n_in,
                              void* d_out, int out_size, void* d_ws, size_t ws_size,
                              hipStream_t stream) {
    const float* x     = (const float*)d_in[0];
    const float* light = (const float*)d_in[1];
    const float* wk  = (const float*)d_in[2];
    const float* bk  = (const float*)d_in[3];
    const float* wq  = (const float*)d_in[4];
    const float* bq  = (const float*)d_in[5];
    const float* wv  = (const float*)d_in[6];
    const float* bv  = (const float*)d_in[7];
    const float* wo  = (const float*)d_in[8];
    const float* bo  = (const float*)d_in[9];
    const float* lw1 = (const float*)d_in[10];
    const float* lb1 = (const float*)d_in[11];
    const float* lw2 = (const float*)d_in[12];
    const float* lb2 = (const float*)d_in[13];
    const float* lw3 = (const float*)d_in[14];
    const float* lb3 = (const float*)d_in[15];
    float* out   = (float*)d_out;
    uint16_t* le = (uint16_t*)d_ws;   // 4*33*33*32 bf16 = 278 KB

    light_emb_kernel<<<dim3((4 * 33 * 33 + 255) / 256), dim3(256), 0, stream>>>(
        light, lw1, lb1, lw2, lb2, lw3, lb3, le);
    fused_attn_kernel<<<dim3(2048), dim3(TB), 0, stream>>>(
        x, wk, bk, wq, bq, wv, bv, wo, bo, le, out);
}